// Round 5
// baseline (84.875 us; speedup 1.0000x reference)
//
#include <hip/hip_runtime.h>
#include <math.h>

#define MX 64
#define NC 4
#define NI 66          // MX + 2
#define NINT 62        // interior tridiagonal unknowns (c2..c63)

typedef _Float16 half4  __attribute__((ext_vector_type(4)));
typedef _Float16 half8  __attribute__((ext_vector_type(8)));
typedef _Float16 half2v __attribute__((ext_vector_type(2)));
typedef float    fx4    __attribute__((ext_vector_type(4)));  // clang-native: OK for nontemporal builtins

// ---------------------------------------------------------------------------
// Compile-time Thomas constants for the (1/6, 2/3, 1/6) tridiagonal system.
// ---------------------------------------------------------------------------
struct TC { float m[NINT]; float inv[NINT]; };
constexpr TC make_tc() {
    TC tc{};
    double dp = 2.0/3.0;
    tc.m[0] = 0.0f;
    tc.inv[0] = (float)(1.0/dp);
    for (int j = 1; j < NINT; ++j) {
        double m = (1.0/6.0) / dp;
        tc.m[j] = (float)m;
        dp = 2.0/3.0 - m*(1.0/6.0);
        tc.inv[j] = (float)(1.0/dp);
    }
    return tc;
}
__constant__ constexpr TC g_tc = make_tc();

// ---------------------------------------------------------------------------
// Dual-parity pair tables -> all gathers are aligned ds_read_b128.
// TA (chS): 66 x-rows of 66 half4 entries (528 B/row); pair k = y {2k,2k+1}.
// TB: 66 x-rows, 32 pairs + 16 B pad = 528 B/row; pair k = y {2k+1,2k+2}.
//   (stride 512->528 so the bank-start index depends on ix for BOTH tables —
//    512 B is 0 mod 32 dwords and dropped ix from the bank hash — and
//    rstride becomes uniform, removing a select.)
// A 4-entry row fetch y0..y0+3 is two aligned b128 from TA (y0 even) or TB
// (y0 odd). 8 wide gathers/pt; FMA order identical to the b64 version.
// ---------------------------------------------------------------------------
__device__ __forceinline__ fx4 eval_pt(const char* __restrict__ taB,
                                       const char* __restrict__ tbB,
                                       float ux, float uy)
{
    const float unx = ux * 63.0f;
    const float uny = uy * 63.0f;

    // i = min(trunc(un), 62); t = un - i   (== reference _axis_index for u in [0,1])
    int ix = (int)unx; ix = ix > 62 ? 62 : ix;
    int iy = (int)uny; iy = iy > 62 ? 62 : iy;
    const float tx = unx - (float)ix;
    const float ty = uny - (float)iy;

    // packed (tx,ty) basis, coefficients pre-divided by 6
    const half2v t = __builtin_bit_cast(half2v, __builtin_amdgcn_cvt_pkrtz(tx, ty));
    const half2v c16  = half2v{(_Float16)(1.0f/6.0f), (_Float16)(1.0f/6.0f)};
    const half2v ch   = half2v{(_Float16)0.5f,  (_Float16)0.5f};
    const half2v cnh  = half2v{(_Float16)-0.5f, (_Float16)-0.5f};
    const half2v cn16 = half2v{(_Float16)(-1.0f/6.0f), (_Float16)(-1.0f/6.0f)};
    const half2v cn1  = half2v{(_Float16)-1.0f, (_Float16)-1.0f};
    const half2v c23  = half2v{(_Float16)(2.0f/3.0f), (_Float16)(2.0f/3.0f)};

    const half2v t2 = t*t;
    half2v b0 = (cn16*t + ch)*t;  b0 = (b0 + cnh)*t + c16;   // (bx0, by0)
    half2v b1 = (ch*t + cn1)*t2 + c23;                        // (bx1, by1)
    half2v b2 = (cnh*t + ch)*t;   b2 = (b2 + ch)*t + c16;     // (bx2, by2)
    half2v b3 = c16*(t*t2);                                   // (bx3, by3)

    // broadcast halves (op_sel-foldable)
    const half2v by0 = __builtin_shufflevector(b0, b0, 1, 1);
    const half2v by1 = __builtin_shufflevector(b1, b1, 1, 1);
    const half2v by2 = __builtin_shufflevector(b2, b2, 1, 1);
    const half2v by3 = __builtin_shufflevector(b3, b3, 1, 1);
    const half2v bx[4] = {
        __builtin_shufflevector(b0, b0, 0, 0),
        __builtin_shufflevector(b1, b1, 0, 0),
        __builtin_shufflevector(b2, b2, 0, 0),
        __builtin_shufflevector(b3, b3, 0, 0),
    };

    // parity-selected table: even iy -> TA pair iy/2; odd iy -> TB pair iy>>1
    const int odd = iy & 1;
    const int ke  = iy >> 1;
    const char* rp = (odd ? tbB : taB) + ix*528 + ke*16;

    half2v t01, t23;
    #pragma unroll
    for (int ar = 0; ar < 4; ++ar) {
        const half8 p0 = *(const half8*)(rp);        // entries y0, y0+1 (4ch each)
        const half8 p1 = *(const half8*)(rp + 16);   // entries y0+2, y0+3
        rp += 528;
        const half2v e0c01 = __builtin_shufflevector(p0, p0, 0, 1);
        const half2v e0c23 = __builtin_shufflevector(p0, p0, 2, 3);
        const half2v e1c01 = __builtin_shufflevector(p0, p0, 4, 5);
        const half2v e1c23 = __builtin_shufflevector(p0, p0, 6, 7);
        const half2v e2c01 = __builtin_shufflevector(p1, p1, 0, 1);
        const half2v e2c23 = __builtin_shufflevector(p1, p1, 2, 3);
        const half2v e3c01 = __builtin_shufflevector(p1, p1, 4, 5);
        const half2v e3c23 = __builtin_shufflevector(p1, p1, 6, 7);
        half2v a01 = e0c01*by0 + e1c01*by1 + e2c01*by2 + e3c01*by3;
        half2v a23 = e0c23*by0 + e1c23*by1 + e2c23*by2 + e3c23*by3;
        if (ar == 0) { t01 = a01*bx[0];        t23 = a23*bx[0]; }
        else         { t01 = a01*bx[ar] + t01; t23 = a23*bx[ar] + t23; }
    }
    return fx4{(float)t01.x, (float)t01.y, (float)t23.x, (float)t23.y};
}

// ---------------------------------------------------------------------------
// Single fused kernel. Every block redundantly solves the 4x(64x64) system
// into LDS (deterministic -> bit-identical in every block). The fp32 x-pass
// scratch (34,320 B) is overlaid by TB (34,848 B) after the solve:
// LDS = 34,848 + 34,848 = 69,696 B -> 2 blocks/CU.
//
// Main-loop: 4-deep u-load batching (4 fx4 loads in flight, then 8
// independent eval chains, then 8 nontemporal stores) to amortize HBM load
// latency 8x — at 4 waves/SIMD there is not enough TLP to hide a per-point
// serial load->gather->store chain.
// ---------------------------------------------------------------------------
__global__ __launch_bounds__(512, 2) void fused(const fx4* __restrict__ u2,
                                                const float* __restrict__ data,
                                                fx4* __restrict__ out, int NB)
{
    __shared__ __align__(16) half4 chS[NI*NI];     // TA: 34,848 B
    __shared__ __align__(16) char  arenaB[NI*528]; // scratch / TB union: 34,848 B
    float (*cxS)[NI][65] = (float(*)[NI][65])arenaB;
    const int t = threadIdx.x;
    const float a = 1.0f/6.0f;

    #pragma unroll
    for (int c2 = 0; c2 < 2; ++c2) {
        // ---- Phase A: x-pass for channels {2*c2, 2*c2+1}: 128 lines ----
        if (t < 128) {
            const int cl = t >> 6, y = t & 63;
            const int c  = c2*2 + cl;
            const float* g = data + c*(MX*MX) + y;
            float w[NINT];
            const float d0 = g[0];
            #pragma unroll
            for (int j = 0; j < NINT; ++j) w[j] = g[(j+1)*MX];   // prefetch all
            const float dM = g[63*MX];
            w[0]      -= a*d0;
            w[NINT-1] -= a*dM;
            #pragma unroll
            for (int j = 1; j < NINT; ++j) w[j] -= g_tc.m[j]*w[j-1];
            float x = w[NINT-1] * g_tc.inv[NINT-1];
            const float c63 = x;
            cxS[cl][63][y] = x;
            #pragma unroll
            for (int j = NINT-2; j >= 0; --j) {
                x = (w[j] - a*x) * g_tc.inv[j];
                cxS[cl][j+2][y] = x;
            }
            cxS[cl][0][y]  = 2.0f*d0 - x;
            cxS[cl][1][y]  = d0;
            cxS[cl][64][y] = dM;
            cxS[cl][65][y] = 2.0f*dM - c63;
        }
        __syncthreads();

        // ---- Phase B: y-pass, 132 lines; results -> fp16 table (TA) ----
        if (t < 2*NI) {
            const int cl = t / NI;
            const int i  = t - cl*NI;
            const int c  = c2*2 + cl;
            const float* g = &cxS[cl][i][0];
            _Float16* o = ((_Float16*)&chS[i*NI]) + c;

            float w[NINT];
            const float d0 = g[0];
            #pragma unroll
            for (int j = 0; j < NINT; ++j) w[j] = g[j+1];
            const float dM = g[63];
            w[0]      -= a*d0;
            w[NINT-1] -= a*dM;
            #pragma unroll
            for (int j = 1; j < NINT; ++j) w[j] -= g_tc.m[j]*w[j-1];
            float x = w[NINT-1] * g_tc.inv[NINT-1];
            const float c63 = x;
            o[63*NC] = (_Float16)x;
            #pragma unroll
            for (int j = NINT-2; j >= 0; --j) {
                x = (w[j] - a*x) * g_tc.inv[j];
                o[(j+2)*NC] = (_Float16)x;
            }
            o[0*NC]  = (_Float16)(2.0f*d0 - x);
            o[1*NC]  = (_Float16)d0;
            o[64*NC] = (_Float16)dM;
            o[65*NC] = (_Float16)(2.0f*dM - c63);
        }
        __syncthreads();   // also protects cxS reuse by next chunk
    }

    // ---- Build TB (shifted pair table, 528 B rows) over the dead scratch ----
    {
        half4* TB4 = (half4*)arenaB;            // 66 half4 per row (incl. pad)
        for (int s = t; s < NI*32; s += 512) {
            const int i = s >> 5, k = s & 31;
            const half4* src = chS + i*NI + 2*k + 1;
            TB4[i*66 + 2*k]     = src[0];
            TB4[i*66 + 2*k + 1] = src[1];
        }
    }
    __syncthreads();

    // ---- Interpolation main loop: 4-deep batched pairs per thread ----
    const char* taB = (const char*)chS;
    const char* tbB = (const char*)arenaB;
    const int STRIDE = gridDim.x * 512;
    for (int b0 = blockIdx.x*512 + t; b0 < NB; b0 += 4*STRIDE) {
        fx4  ua[4];
        bool ok[4];
        #pragma unroll
        for (int k = 0; k < 4; ++k) {
            const int b = b0 + k*STRIDE;
            ok[k] = (b < NB);
            if (ok[k]) ua[k] = __builtin_nontemporal_load(&u2[b]);
        }
        #pragma unroll
        for (int k = 0; k < 4; ++k) {
            if (ok[k]) {
                const int b = b0 + k*STRIDE;
                const fx4 v0 = eval_pt(taB, tbB, ua[k].x, ua[k].y);
                const fx4 v1 = eval_pt(taB, tbB, ua[k].z, ua[k].w);
                __builtin_nontemporal_store(v0, &out[2*b]);
                __builtin_nontemporal_store(v1, &out[2*b+1]);
            }
        }
    }
}

extern "C" void kernel_launch(void* const* d_in, const int* in_sizes, int n_in,
                              void* d_out, int out_size, void* d_ws, size_t ws_size,
                              hipStream_t stream)
{
    const float* u    = (const float*)d_in[0];   // (B,2)
    const float* data = (const float*)d_in[1];   // (4,64,64)
    const int B  = in_sizes[0] / 2;              // 2,000,000
    const int NB = B / 2;                        // point pairs (B is even)

    // 512 blocks = exactly 2 resident blocks/CU (LDS-limited), so every
    // block's in-LDS solve is paid once, concurrently.
    fused<<<512, 512, 0, stream>>>((const fx4*)u, data, (fx4*)d_out, NB);
}

// Round 6
// 82.654 us; speedup vs baseline: 1.0269x; 1.0269x over previous
//
#include <hip/hip_runtime.h>
#include <math.h>

#define MX 64
#define NC 4
#define NI 66          // MX + 2
#define NINT 62        // interior tridiagonal unknowns (c2..c63)

typedef _Float16 half4  __attribute__((ext_vector_type(4)));
typedef _Float16 half8  __attribute__((ext_vector_type(8)));
typedef _Float16 half2v __attribute__((ext_vector_type(2)));
typedef float    fx4    __attribute__((ext_vector_type(4)));

// ---------------------------------------------------------------------------
// Compile-time Thomas constants for the (1/6, 2/3, 1/6) tridiagonal system.
// ---------------------------------------------------------------------------
struct TC { float m[NINT]; float inv[NINT]; };
constexpr TC make_tc() {
    TC tc{};
    double dp = 2.0/3.0;
    tc.m[0] = 0.0f;
    tc.inv[0] = (float)(1.0/dp);
    for (int j = 1; j < NINT; ++j) {
        double m = (1.0/6.0) / dp;
        tc.m[j] = (float)m;
        dp = 2.0/3.0 - m*(1.0/6.0);
        tc.inv[j] = (float)(1.0/dp);
    }
    return tc;
}
__constant__ constexpr TC g_tc = make_tc();

// ---------------------------------------------------------------------------
// Dual-parity pair tables -> all gathers are aligned ds_read_b128.
// TA: 66 x-rows of 66 half4 entries (528 B/row); pair k covers y {2k,2k+1}.
// TB: 66 x-rows, 32 pairs + 16 B pad = 528 B/row; pair k covers y {2k+1,2k+2}.
// A 4-entry row fetch y0..y0+3 is two aligned b128 from TA (y0 even) or TB
// (y0 odd). 8 wide gathers/pt (128 B stencil / 16 B per b128 = irreducible).
// All 8 DS offsets are compile-time constants off one base VGPR.
// ---------------------------------------------------------------------------
__device__ __forceinline__ fx4 eval_pt(const char* __restrict__ taB,
                                       const char* __restrict__ tbB,
                                       float ux, float uy)
{
    const float unx = ux * 63.0f;
    const float uny = uy * 63.0f;

    // i = min(trunc(un), 62); t = un - i   (== reference _axis_index for u in [0,1])
    int ix = (int)unx; ix = ix > 62 ? 62 : ix;
    int iy = (int)uny; iy = iy > 62 ? 62 : iy;
    const float tx = unx - (float)ix;
    const float ty = uny - (float)iy;

    // packed (tx,ty) basis, coefficients pre-divided by 6
    const half2v t = __builtin_bit_cast(half2v, __builtin_amdgcn_cvt_pkrtz(tx, ty));
    const half2v c16  = half2v{(_Float16)(1.0f/6.0f), (_Float16)(1.0f/6.0f)};
    const half2v ch   = half2v{(_Float16)0.5f,  (_Float16)0.5f};
    const half2v cnh  = half2v{(_Float16)-0.5f, (_Float16)-0.5f};
    const half2v cn16 = half2v{(_Float16)(-1.0f/6.0f), (_Float16)(-1.0f/6.0f)};
    const half2v cn1  = half2v{(_Float16)-1.0f, (_Float16)-1.0f};
    const half2v c23  = half2v{(_Float16)(2.0f/3.0f), (_Float16)(2.0f/3.0f)};

    const half2v t2 = t*t;
    half2v b0 = (cn16*t + ch)*t;  b0 = (b0 + cnh)*t + c16;   // (bx0, by0)
    half2v b1 = (ch*t + cn1)*t2 + c23;                        // (bx1, by1)
    half2v b2 = (cnh*t + ch)*t;   b2 = (b2 + ch)*t + c16;     // (bx2, by2)
    half2v b3 = c16*(t*t2);                                   // (bx3, by3)

    // broadcast halves (op_sel-foldable)
    const half2v by0 = __builtin_shufflevector(b0, b0, 1, 1);
    const half2v by1 = __builtin_shufflevector(b1, b1, 1, 1);
    const half2v by2 = __builtin_shufflevector(b2, b2, 1, 1);
    const half2v by3 = __builtin_shufflevector(b3, b3, 1, 1);
    const half2v bx[4] = {
        __builtin_shufflevector(b0, b0, 0, 0),
        __builtin_shufflevector(b1, b1, 0, 0),
        __builtin_shufflevector(b2, b2, 0, 0),
        __builtin_shufflevector(b3, b3, 0, 0),
    };

    // parity-selected table: even iy -> TA pair iy/2; odd iy -> TB pair iy>>1
    const int odd = iy & 1;
    const int ke  = iy >> 1;
    const char* rp = (odd ? tbB : taB) + ix*528 + ke*16;

    half2v t01, t23;
    #pragma unroll
    for (int ar = 0; ar < 4; ++ar) {
        const half8 p0 = *(const half8*)(rp + ar*528);        // y0, y0+1 (4ch each)
        const half8 p1 = *(const half8*)(rp + ar*528 + 16);   // y0+2, y0+3
        const half2v e0c01 = __builtin_shufflevector(p0, p0, 0, 1);
        const half2v e0c23 = __builtin_shufflevector(p0, p0, 2, 3);
        const half2v e1c01 = __builtin_shufflevector(p0, p0, 4, 5);
        const half2v e1c23 = __builtin_shufflevector(p0, p0, 6, 7);
        const half2v e2c01 = __builtin_shufflevector(p1, p1, 0, 1);
        const half2v e2c23 = __builtin_shufflevector(p1, p1, 2, 3);
        const half2v e3c01 = __builtin_shufflevector(p1, p1, 4, 5);
        const half2v e3c23 = __builtin_shufflevector(p1, p1, 6, 7);
        half2v a01 = e0c01*by0 + e1c01*by1 + e2c01*by2 + e3c01*by3;
        half2v a23 = e0c23*by0 + e1c23*by1 + e2c23*by2 + e3c23*by3;
        if (ar == 0) { t01 = a01*bx[0];        t23 = a23*bx[0]; }
        else         { t01 = a01*bx[ar] + t01; t23 = a23*bx[ar] + t23; }
    }
    return fx4{(float)t01.x, (float)t01.y, (float)t23.x, (float)t23.y};
}

// ---------------------------------------------------------------------------
// Single fused kernel. Every block redundantly solves the 4x(64x64) system
// into LDS (deterministic -> bit-identical in every block). The fp32 x-pass
// scratch (34,320 B) is overlaid by TB (34,848 B) after the solve:
// LDS = 34,848 + 34,848 = 69,696 B -> 2 blocks/CU.
// __launch_bounds__(512,4) caps VGPR at 128 so 2-block residency is
// guaranteed (R5's (512,2) allowed VGPR growth -> possible 1-block/CU).
//
// Main loop: TWO points per thread from one float4 u-load; the two eval
// chains' 16 ds_read_b128 interleave, halving exposed lgkmcnt stalls.
// ---------------------------------------------------------------------------
__global__ __launch_bounds__(512, 4) void fused(const fx4* __restrict__ u2,
                                                const float* __restrict__ data,
                                                fx4* __restrict__ out, int NB)
{
    __shared__ __align__(16) half4 chS[NI*NI];     // TA: 34,848 B
    __shared__ __align__(16) char  arenaB[NI*528]; // scratch / TB union: 34,848 B
    float (*cxS)[NI][65] = (float(*)[NI][65])arenaB;
    const int t = threadIdx.x;
    const float a = 1.0f/6.0f;

    #pragma unroll
    for (int c2 = 0; c2 < 2; ++c2) {
        // ---- Phase A: x-pass for channels {2*c2, 2*c2+1}: 128 lines ----
        if (t < 128) {
            const int cl = t >> 6, y = t & 63;
            const int c  = c2*2 + cl;
            const float* g = data + c*(MX*MX) + y;
            float w[NINT];
            const float d0 = g[0];
            #pragma unroll
            for (int j = 0; j < NINT; ++j) w[j] = g[(j+1)*MX];   // prefetch all
            const float dM = g[63*MX];
            w[0]      -= a*d0;
            w[NINT-1] -= a*dM;
            #pragma unroll
            for (int j = 1; j < NINT; ++j) w[j] -= g_tc.m[j]*w[j-1];
            float x = w[NINT-1] * g_tc.inv[NINT-1];
            const float c63 = x;
            cxS[cl][63][y] = x;
            #pragma unroll
            for (int j = NINT-2; j >= 0; --j) {
                x = (w[j] - a*x) * g_tc.inv[j];
                cxS[cl][j+2][y] = x;
            }
            cxS[cl][0][y]  = 2.0f*d0 - x;
            cxS[cl][1][y]  = d0;
            cxS[cl][64][y] = dM;
            cxS[cl][65][y] = 2.0f*dM - c63;
        }
        __syncthreads();

        // ---- Phase B: y-pass, 132 lines; results -> fp16 table (TA) ----
        if (t < 2*NI) {
            const int cl = t / NI;
            const int i  = t - cl*NI;
            const int c  = c2*2 + cl;
            const float* g = &cxS[cl][i][0];
            _Float16* o = ((_Float16*)&chS[i*NI]) + c;

            float w[NINT];
            const float d0 = g[0];
            #pragma unroll
            for (int j = 0; j < NINT; ++j) w[j] = g[j+1];
            const float dM = g[63];
            w[0]      -= a*d0;
            w[NINT-1] -= a*dM;
            #pragma unroll
            for (int j = 1; j < NINT; ++j) w[j] -= g_tc.m[j]*w[j-1];
            float x = w[NINT-1] * g_tc.inv[NINT-1];
            const float c63 = x;
            o[63*NC] = (_Float16)x;
            #pragma unroll
            for (int j = NINT-2; j >= 0; --j) {
                x = (w[j] - a*x) * g_tc.inv[j];
                o[(j+2)*NC] = (_Float16)x;
            }
            o[0*NC]  = (_Float16)(2.0f*d0 - x);
            o[1*NC]  = (_Float16)d0;
            o[64*NC] = (_Float16)dM;
            o[65*NC] = (_Float16)(2.0f*dM - c63);
        }
        __syncthreads();   // also protects cxS reuse by next chunk
    }

    // ---- Build TB (shifted pair table, 528 B rows) over the dead scratch ----
    {
        half4* TB4 = (half4*)arenaB;            // 66 half4 per row (incl. pad)
        for (int s = t; s < NI*32; s += 512) {
            const int i = s >> 5, k = s & 31;
            const half4* src = chS + i*NI + 2*k + 1;
            TB4[i*66 + 2*k]     = src[0];
            TB4[i*66 + 2*k + 1] = src[1];
        }
    }
    __syncthreads();

    // ---- Interpolation main loop: two points per thread (one float4) ----
    const char* taB = (const char*)chS;
    const char* tbB = (const char*)arenaB;
    const int STRIDE = gridDim.x * 512;
    for (int b = blockIdx.x*512 + t; b < NB; b += STRIDE) {
        const fx4 uu = u2[b];                       // (x0,y0,x1,y1) — two points
        const fx4 v0 = eval_pt(taB, tbB, uu.x, uu.y);
        const fx4 v1 = eval_pt(taB, tbB, uu.z, uu.w);
        out[2*b]   = v0;
        out[2*b+1] = v1;
    }
}

extern "C" void kernel_launch(void* const* d_in, const int* in_sizes, int n_in,
                              void* d_out, int out_size, void* d_ws, size_t ws_size,
                              hipStream_t stream)
{
    const float* u    = (const float*)d_in[0];   // (B,2)
    const float* data = (const float*)d_in[1];   // (4,64,64)
    const int B  = in_sizes[0] / 2;              // 2,000,000
    const int NB = B / 2;                        // point pairs (B is even)

    // 512 blocks = exactly 2 resident blocks/CU (LDS-limited), so every
    // block's in-LDS solve is paid once, concurrently.
    fused<<<512, 512, 0, stream>>>((const fx4*)u, data, (fx4*)d_out, NB);
}